// Round 21
// baseline (214.248 us; speedup 1.0000x reference)
//
#include <hip/hip_runtime.h>
#include <hip/hip_bf16.h>
#include <math.h>

#define D   128
#define FFD 512
#define NPART 8
#define BINB 1024
#define BCAP 768
#define NPROD 32
#define NSUB 32
#define RCAP 320

typedef __attribute__((ext_vector_type(8))) short bf16x8;
typedef __attribute__((ext_vector_type(4))) float f32x4;
typedef __attribute__((ext_vector_type(2))) float f32x2;

static inline size_t align256(size_t x){ return (x + 255) & ~(size_t)255; }

__device__ __forceinline__ float bf2f(unsigned short u){
    union { unsigned int i; float f; } x; x.i = ((unsigned int)u) << 16; return x.f;
}
__device__ __forceinline__ unsigned short f2bf(float f){
    return __builtin_bit_cast(unsigned short, __float2bfloat16(f));
}
// single fp8 e4m3 encode (OCP on gfx950)
__device__ __forceinline__ unsigned char f2fp8(float f){
    return (unsigned char)(__builtin_amdgcn_cvt_pk_fp8_f32(f, f, 0, false) & 0xff);
}

// DPP butterfly add (quad_perm within 4-lane groups)
#define DPP_ADD(x, ctrl) do { \
    int yi_ = __builtin_amdgcn_update_dpp(0, __builtin_bit_cast(int, x), ctrl, 0xf, 0xf, true); \
    x += __builtin_bit_cast(float, yi_); } while(0)

// ---------------- CSR build v7: two-level bin, 3-kernel count/scan/scatter ------
__global__ __launch_bounds__(256) void k_bin3(const int* __restrict__ src,
                                              const int* __restrict__ dst, int E, int N,
                                              unsigned long long* __restrict__ pairs,
                                              int* __restrict__ lens,
                                              unsigned long long* __restrict__ spill,
                                              int* __restrict__ qspill){
    __shared__ int lcur[8];
    int tid = threadIdx.x;
    if (tid < 8) lcur[tid] = 0;
    __syncthreads();
    int slice = (N + 7) >> 3;
    int T = gridDim.x * 256;
    unsigned long long* myreg = pairs + (size_t)blockIdx.x * 8 * BCAP;
    for (int i = blockIdx.x*256 + tid; i < E; i += T){
        int d = __builtin_nontemporal_load(&dst[i]);
        int s = __builtin_nontemporal_load(&src[i]);
        int b = min(d / slice, 7);
        unsigned long long pr = ((unsigned long long)(unsigned)d << 32) | (unsigned)s;
        int slot = atomicAdd(&lcur[b], 1);
        if (slot < BCAP) myreg[(size_t)b*BCAP + slot] = pr;
        else { int p = atomicAdd(qspill, 1); spill[p] = pr; }   // ~never
    }
    __syncthreads();
    if (tid < 8) lens[blockIdx.x*8 + tid] = min(lcur[tid], BCAP);
}

__global__ __launch_bounds__(256) void k_rebin(const unsigned long long* __restrict__ pairs,
                                               const int* __restrict__ lens,
                                               unsigned* __restrict__ pairs2,
                                               int* __restrict__ rlens,
                                               unsigned long long* __restrict__ spill,
                                               int* __restrict__ qspill, int N){
    __shared__ int lcur[NSUB];
    int part = blockIdx.x & 7, ip = blockIdx.x >> 3;
    int tid = threadIdx.x;
    if (tid < NSUB) lcur[tid] = 0;
    __syncthreads();
    int slice = (N + 7) >> 3;
    unsigned subslice = (unsigned)(slice + NSUB - 1) / NSUB;
    int lo_part = part * slice;
    unsigned* outbase = pairs2 + (size_t)(part*NPROD + ip) * NSUB * RCAP;
    for (int seg = ip*(BINB/NPROD); seg < (ip+1)*(BINB/NPROD); ++seg){
        int len = lens[seg*8 + part];
        const unsigned long long* pp = pairs + ((size_t)seg*8 + part)*BCAP;
        for (int i = tid; i < len; i += 256){
            unsigned long long pr = pp[i];
            int d = (int)(pr >> 32);
            unsigned dl = (unsigned)(d - lo_part);
            unsigned sb = dl / subslice;
            int slot = atomicAdd(&lcur[sb], 1);
            if (slot < RCAP)
                outbase[(size_t)sb*RCAP + slot] = ((dl - sb*subslice) << 24) | (unsigned)pr & 0xFFFFFFu;
            else { int p = atomicAdd(qspill, 1); spill[p] = pr; }  // ~never
        }
    }
    __syncthreads();
    if (tid < NSUB) rlens[(part*NPROD + ip)*NSUB + tid] = min(lcur[tid], RCAP);
}

// k_count5: block (p,s) owns ~196 nodes: LDS histogram over its pairs, then
// store hist row to global + block total (replaces cnt[] pass + k_bsum).
__global__ __launch_bounds__(256) void k_count5(const unsigned* __restrict__ pairs2,
                                                const int* __restrict__ rlens,
                                                const unsigned long long* __restrict__ spill,
                                                const int* __restrict__ qspill,
                                                int* __restrict__ hist2g,
                                                int* __restrict__ bsum256, int N){
    __shared__ int hist[256];
    __shared__ int w4[4];
    int part = blockIdx.x & 7, s = blockIdx.x >> 3;
    int slice = (N + 7) >> 3;
    int subslice = (slice + NSUB - 1) / NSUB;
    int lo_part = part*slice;
    int lo = lo_part + s*subslice;
    int part_end = min(lo_part + slice, N);
    int n_sub = max(0, min(subslice, part_end - lo));
    hist[threadIdx.x] = 0;
    __syncthreads();
    for (int ip = 0; ip < NPROD; ++ip){
        int r = (part*NPROD + ip)*NSUB + s;
        int len = rlens[r];
        const unsigned* pp = pairs2 + (size_t)r*RCAP;
        for (int i = threadIdx.x; i < len; i += 256)
            atomicAdd(&hist[pp[i] >> 24], 1);
    }
    int ns = *qspill;
    for (int i = threadIdx.x; i < ns; i += 256){
        int r = (int)(spill[i] >> 32) - lo;
        if (r >= 0 && r < n_sub) atomicAdd(&hist[r], 1);
    }
    __syncthreads();
    int v = hist[threadIdx.x];
    hist2g[blockIdx.x*256 + threadIdx.x] = v;
    #pragma unroll
    for (int o = 1; o < 64; o <<= 1) v += __shfl_xor(v, o);
    if ((threadIdx.x & 63) == 0) w4[threadIdx.x >> 6] = v;
    __syncthreads();
    if (threadIdx.x == 0) bsum256[blockIdx.x] = w4[0] + w4[1] + w4[2] + w4[3];
}

// k_scanb: scan in NODE order. Node range of physical block (part,s) starts at
// part*slice + s*subslice, so logical order l = part*32 + s; physical index
// (blockIdx of count/scatter) = s*8 + part. Read/write through that permutation.
__global__ __launch_bounds__(1024) void k_scanb(const int* __restrict__ bsum, int NB,
                                                int* __restrict__ ebase,
                                                int* __restrict__ off, int N){
    __shared__ int sh[1024];
    int tid = threadIdx.x;
    int phys = ((tid & 31) << 3) | (tid >> 5);   // valid for tid < 256
    int v = (tid < NB) ? bsum[phys] : 0;
    sh[tid] = v; __syncthreads();
    for (int o = 1; o < 1024; o <<= 1){
        int t = (tid >= o) ? sh[tid-o] : 0;
        __syncthreads();
        sh[tid] += t;
        __syncthreads();
    }
    if (tid < NB) ebase[phys] = sh[tid] - v;
    if (tid == NB-1) off[N] = sh[tid];
}

// k_scatter5: block (p,s): load its hist row, LDS prefix-scan + ebase -> writes
// off[] for its range and scatters csr into the private contiguous slice.
__global__ __launch_bounds__(256) void k_scatter5(const unsigned* __restrict__ pairs2,
                                                  const int* __restrict__ rlens,
                                                  const unsigned long long* __restrict__ spill,
                                                  const int* __restrict__ qspill,
                                                  const int* __restrict__ hist2g,
                                                  const int* __restrict__ ebase,
                                                  int* __restrict__ off,
                                                  int* __restrict__ csr_src, int N){
    __shared__ int sh[256];
    __shared__ int curl[256];
    int part = blockIdx.x & 7, s = blockIdx.x >> 3;
    int tid = threadIdx.x;
    int slice = (N + 7) >> 3;
    int subslice = (slice + NSUB - 1) / NSUB;
    int lo_part = part*slice;
    int lo = lo_part + s*subslice;
    int part_end = min(lo_part + slice, N);
    int n_sub = max(0, min(subslice, part_end - lo));
    int v = hist2g[blockIdx.x*256 + tid];
    sh[tid] = v; __syncthreads();
    for (int o = 1; o < 256; o <<= 1){
        int t = (tid >= o) ? sh[tid-o] : 0;
        __syncthreads();
        sh[tid] += t;
        __syncthreads();
    }
    int base = ebase[blockIdx.x];
    int start = base + sh[tid] - v;
    curl[tid] = start;
    if (tid < n_sub) off[lo + tid] = start;
    __syncthreads();
    for (int ip = 0; ip < NPROD; ++ip){
        int r = (part*NPROD + ip)*NSUB + s;
        int len = rlens[r];
        const unsigned* pp = pairs2 + (size_t)r*RCAP;
        for (int i = tid; i < len; i += 256){
            unsigned e = pp[i];
            int pos = atomicAdd(&curl[e >> 24], 1);
            csr_src[pos] = (int)(e & 0xFFFFFFu);
        }
    }
    int ns = *qspill;
    for (int i = tid; i < ns; i += 256){
        unsigned long long pr = spill[i];
        int r = (int)(pr >> 32) - lo;
        if (r >= 0 && r < n_sub){
            int pos = atomicAdd(&curl[r], 1);
            csr_src[pos] = (int)(unsigned)pr;
        }
    }
}

// ---------------- prep ----------------
__global__ __launch_bounds__(256) void k_cast(const float* __restrict__ x,
                                              __hip_bfloat16* __restrict__ y, int n4){
    int i = blockIdx.x*blockDim.x + threadIdx.x;
    if (i >= n4) return;
    float4 f = ((const float4*)x)[i];
    ushort4 u;
    u.x = f2bf(f.x); u.y = f2bf(f.y);
    u.z = f2bf(f.z); u.w = f2bf(f.w);
    ((ushort4*)y)[i] = u;
}

// merged weight transpose+cast. Wk/Wv rows permuted for the 32-lane attn layout.
__global__ __launch_bounds__(256) void k_prep_all(
    const float* __restrict__ Wq, const float* __restrict__ Wk,
    const float* __restrict__ Wv, const float* __restrict__ Wo,
    const float* __restrict__ W1, const float* __restrict__ W2,
    __hip_bfloat16* __restrict__ Wqkvt, __hip_bfloat16* __restrict__ Wot,
    __hip_bfloat16* __restrict__ W1t,   __hip_bfloat16* __restrict__ W2t){
    const float* W; __hip_bfloat16* Wt; int K, Nc;
    int y = blockIdx.y;
    switch (y){
        case 0: W = Wq; Wt = Wqkvt; K = 128; Nc = 128; break;
        case 1: W = Wk; Wt = Wqkvt; K = 128; Nc = 128; break;
        case 2: W = Wv; Wt = Wqkvt; K = 128; Nc = 128; break;
        case 3: W = Wo; Wt = Wot;   K = 128; Nc = 128; break;
        case 4: W = W1; Wt = W1t;   K = 128; Nc = 512; break;
        default: W = W2; Wt = W2t;  K = 512; Nc = 128; break;
    }
    int total = K*Nc;
    for (int id = blockIdx.x*256 + threadIdx.x; id < total; id += 256*gridDim.x){
        int n = id / K, kk = id % K;
        size_t drow;
        if (y == 1)      drow = 128 + 8*(n>>2) + (n&3);
        else if (y == 2) drow = 128 + 8*(n>>2) + 4 + (n&3);
        else             drow = n;
        Wt[drow*K + kk] = __float2bfloat16(W[(size_t)kk*Nc + n]);
    }
}

// ---------------- MFMA helpers ----------------
#define BM 128
#define BN 128
#define BK 64

__device__ __forceinline__ bool tile_coords(int M, int &r0, int &c0){
    int ncols = gridDim.x;
    int f = blockIdx.y * ncols + blockIdx.x;
    int xcd = f & 7, s = f >> 3;
    int c = s % ncols, rl = s / ncols;
    int r = rl*8 + xcd;
    r0 = r*BM; c0 = c*BN;
    return r0 < M;
}

// stage 128 rows x 64 K (bf16), XOR-swizzled source (256-thread version)
__device__ __forceinline__ void stage_tile(const __hip_bfloat16* __restrict__ src,
                                           int row_base, int row_limit, int ldK, int k0,
                                           __hip_bfloat16* lds){
    int tid = threadIdx.x;
    int wave = tid >> 6;
    #pragma unroll
    for (int i = 0; i < 4; ++i){
        int c = i*256 + tid;
        int r = c >> 3, s = c & 7;
        int sg = s ^ (r & 7);
        int gr = row_base + r; if (gr >= row_limit) gr = row_limit - 1;
        const __hip_bfloat16* gp = src + (size_t)gr*ldK + k0 + sg*8;
        char* lp = (char*)lds + (i*256 + wave*64)*16;
        __builtin_amdgcn_global_load_lds((const __attribute__((address_space(1))) void*)gp,
                                         (__attribute__((address_space(3))) void*)lp,
                                         16, 0, 0);
    }
}

// 512-thread versions
__device__ __forceinline__ void stage_tile512(const __hip_bfloat16* __restrict__ src,
                                              int row_base, int row_limit, int ldK, int k0,
                                              __hip_bfloat16* lds){
    int tid = threadIdx.x;
    int wave = tid >> 6;
    #pragma unroll
    for (int i = 0; i < 2; ++i){
        int c = i*512 + tid;
        int r = c >> 3, s = c & 7;
        int sg = s ^ (r & 7);
        int gr = row_base + r; if (gr >= row_limit) gr = row_limit - 1;
        const __hip_bfloat16* gp = src + (size_t)gr*ldK + k0 + sg*8;
        char* lp = (char*)lds + (i*512 + wave*64)*16;
        __builtin_amdgcn_global_load_lds((const __attribute__((address_space(1))) void*)gp,
                                         (__attribute__((address_space(3))) void*)lp,
                                         16, 0, 0);
    }
}

// 64 rows x 64 K, 512 threads, no clamp (full weight rows)
__device__ __forceinline__ void stage_rows64_512(const __hip_bfloat16* __restrict__ src,
                                                 int row_base, int ldK, int k0,
                                                 __hip_bfloat16* lds){
    int tid = threadIdx.x;
    int wave = tid >> 6;
    int c = tid;                      // 512 chunks = 64 rows x 8 slots
    int r = c >> 3, s = c & 7;
    int sg = s ^ (r & 7);
    const __hip_bfloat16* gp = src + (size_t)(row_base + r)*ldK + k0 + sg*8;
    char* lp = (char*)lds + (wave*64)*16;
    __builtin_amdgcn_global_load_lds((const __attribute__((address_space(1))) void*)gp,
                                     (__attribute__((address_space(3))) void*)lp,
                                     16, 0, 0);
}

// 64 rows x 64 K, 512 threads, row-clamped (activation tiles)
__device__ __forceinline__ void stage_rows64c_512(const __hip_bfloat16* __restrict__ src,
                                                  int row_base, int row_limit, int ldK, int k0,
                                                  __hip_bfloat16* lds){
    int tid = threadIdx.x;
    int wave = tid >> 6;
    int c = tid;
    int r = c >> 3, s = c & 7;
    int sg = s ^ (r & 7);
    int gr = row_base + r; if (gr >= row_limit) gr = row_limit - 1;
    const __hip_bfloat16* gp = src + (size_t)gr*ldK + k0 + sg*8;
    char* lp = (char*)lds + (wave*64)*16;
    __builtin_amdgcn_global_load_lds((const __attribute__((address_space(1))) void*)gp,
                                     (__attribute__((address_space(3))) void*)lp,
                                     16, 0, 0);
}

// read A/B fragment from a swizzled [rows][64] buffer
__device__ __forceinline__ bf16x8 frag(const __hip_bfloat16* buf, int R, int kk, int ls){
    int sl = (kk*4 + ls) ^ (R & 7);
    return *(const bf16x8*)((const char*)buf + R*128 + sl*16);
}

// ---------------- QKV GEMM ----------------
__global__ __launch_bounds__(256) void k_gemm_qkv(
    const __hip_bfloat16* __restrict__ A,   // [M][128]
    const __hip_bfloat16* __restrict__ Bt,  // [384][128]
    int M,
    __hip_bfloat16* __restrict__ qb, unsigned char* __restrict__ kvq){
    __shared__ __hip_bfloat16 As[BM*BK];
    __shared__ __hip_bfloat16 Bs[BN*BK];
    int r0, c0;
    if (!tile_coords(M, r0, c0)) return;
    int tid = threadIdx.x;
    int lane = tid & 63, wave = tid >> 6;
    int wr = wave >> 1, wc = wave & 1;
    int lr = lane & 15, ls = lane >> 4;

    f32x4 acc[4][4];
    #pragma unroll
    for (int m = 0; m < 4; m++)
        #pragma unroll
        for (int n = 0; n < 4; n++) acc[m][n] = (f32x4){0.f,0.f,0.f,0.f};

    for (int k0 = 0; k0 < 128; k0 += BK){
        stage_tile(A,  r0, M,   128, k0, As);
        stage_tile(Bt, c0, 384, 128, k0, Bs);
        __syncthreads();
        #pragma unroll
        for (int kk = 0; kk < 2; ++kk){
            bf16x8 af[4], bfg[4];
            #pragma unroll
            for (int m = 0; m < 4; m++) af[m]  = frag(As, wr*64 + m*16 + lr, kk, ls);
            #pragma unroll
            for (int n = 0; n < 4; n++) bfg[n] = frag(Bs, wc*64 + n*16 + lr, kk, ls);
            #pragma unroll
            for (int m = 0; m < 4; m++)
                #pragma unroll
                for (int n = 0; n < 4; n++)
                    acc[m][n] = __builtin_amdgcn_mfma_f32_16x16x32_bf16(af[m], bfg[n], acc[m][n], 0, 0, 0);
        }
        __syncthreads();
    }

    int region = c0 >> 7;    // 0=q, 1=kv bytes 0..127, 2=kv bytes 128..255
    #pragma unroll
    for (int n = 0; n < 4; n++){
        int c16 = wc*64 + n*16 + lr;
        #pragma unroll
        for (int m = 0; m < 4; m++){
            #pragma unroll
            for (int j = 0; j < 4; j++){
                int row = r0 + wr*64 + m*16 + ls*4 + j;
                if (row >= M) continue;
                float v = acc[m][n][j];
                if (region == 0)
                    ((unsigned short*)qb)[(size_t)row*128 + c16] = f2bf(v);
                else
                    kvq[(size_t)row*256 + (region-1)*128 + c16] = f2fp8(v);
            }
        }
    }
}

// ---------------- fused tail v4: 64-row blocks, 512 threads, 40KB LDS ----------
#define TBM 64
__global__ __launch_bounds__(512) void k_tail(
    const __hip_bfloat16* __restrict__ ab, const float* __restrict__ h,
    const __hip_bfloat16* __restrict__ Wot,
    const float* __restrict__ ln1g, const float* __restrict__ ln1b,
    const __hip_bfloat16* __restrict__ W1t, const float* __restrict__ b1,
    const __hip_bfloat16* __restrict__ W2t, const float* __restrict__ b2,
    const float* __restrict__ ln2g, const float* __restrict__ ln2b,
    float* __restrict__ out, int M){
    __shared__ char smem[40960];
    __hip_bfloat16* buf0 = (__hip_bfloat16*)smem;            // 8KB
    __hip_bfloat16* buf1 = (__hip_bfloat16*)(smem + 8192);   // 16KB
    __hip_bfloat16* h1s0 = (__hip_bfloat16*)(smem + 24576);  // 8KB
    __hip_bfloat16* h1s1 = (__hip_bfloat16*)(smem + 32768);  // 8KB
    float* red0 = (float*)smem;              // overlay on buf0 (LN phases only)
    float* red1 = (float*)(smem + 1024);
    int f = blockIdx.x;
    int r0 = ((f >> 3)*8 + (f & 7)) * TBM;   // XCD swizzle (bijective, grid%8==0)
    if (r0 >= M) return;
    int tid = threadIdx.x;
    int lane = tid & 63, wave = tid >> 6;
    int wr = wave >> 2, wq = wave & 3;
    int lr = lane & 15, ls = lane >> 4;

    f32x4 acc[2][2];
    #pragma unroll
    for (int m = 0; m < 2; m++)
        #pragma unroll
        for (int n = 0; n < 2; n++) acc[m][n] = (f32x4){0.f,0.f,0.f,0.f};

    // ---- phase A: o = ab @ Wot ----
    for (int k0 = 0; k0 < 128; k0 += BK){
        stage_rows64c_512(ab, r0, M, 128, k0, buf0);
        stage_tile512(Wot, 0, 128, 128, k0, buf1);
        __syncthreads();
        #pragma unroll
        for (int kk = 0; kk < 2; ++kk){
            bf16x8 af[2], bfg[2];
            #pragma unroll
            for (int m = 0; m < 2; m++) af[m]  = frag(buf0, wr*32 + m*16 + lr, kk, ls);
            #pragma unroll
            for (int n = 0; n < 2; n++) bfg[n] = frag(buf1, wq*32 + n*16 + lr, kk, ls);
            #pragma unroll
            for (int m = 0; m < 2; m++)
                #pragma unroll
                for (int n = 0; n < 2; n++)
                    acc[m][n] = __builtin_amdgcn_mfma_f32_16x16x32_bf16(af[m], bfg[n], acc[m][n], 0, 0, 0);
        }
        __syncthreads();
    }

    // ---- phase B: LN1(o + h) -> h1s (buf0 dead; red overlays it) ----
    #pragma unroll
    for (int m = 0; m < 2; m++){
        #pragma unroll
        for (int j = 0; j < 4; j++){
            int rowl = wr*32 + m*16 + ls*4 + j;
            int row = r0 + rowl;
            float s = 0.f, q = 0.f;
            #pragma unroll
            for (int n = 0; n < 2; n++){
                int col = wq*32 + n*16 + lr;
                float rv = (row < M) ? h[(size_t)row*128 + col] : 0.f;
                float v = acc[m][n][j] + rv;
                acc[m][n][j] = v;
                s += v; q += v*v;
            }
            #pragma unroll
            for (int o = 1; o < 16; o <<= 1){
                s += __shfl_xor(s, o);
                q += __shfl_xor(q, o);
            }
            if (lr == 0){
                red0[rowl*4 + wq] = s;
                red1[rowl*4 + wq] = q;
            }
        }
    }
    __syncthreads();
    #pragma unroll
    for (int m = 0; m < 2; m++){
        #pragma unroll
        for (int j = 0; j < 4; j++){
            int rowl = wr*32 + m*16 + ls*4 + j;
            float s4 = red0[rowl*4+0] + red0[rowl*4+1] + red0[rowl*4+2] + red0[rowl*4+3];
            float q4 = red1[rowl*4+0] + red1[rowl*4+1] + red1[rowl*4+2] + red1[rowl*4+3];
            float mu  = s4 * (1.f/128.f);
            float var = fmaxf(q4 * (1.f/128.f) - mu*mu, 0.f);
            float inv = rsqrtf(var + 1e-5f);
            #pragma unroll
            for (int n = 0; n < 2; n++){
                int col = wq*32 + n*16 + lr;
                float o = (acc[m][n][j] - mu)*inv*ln1g[col] + ln1b[col];
                int c6 = col & 63;
                int slot = (c6 >> 3) ^ (rowl & 7), elem = c6 & 7;
                unsigned short* dstp = (unsigned short*)((col >> 6) ? h1s1 : h1s0);
                dstp[rowl*64 + slot*8 + elem] = f2bf(o);
            }
        }
    }
    __syncthreads();

    // ---- phase C: 8 FFN chunks of 64 ff-cols ----
    f32x4 yacc[2][2];
    #pragma unroll
    for (int m = 0; m < 2; m++)
        #pragma unroll
        for (int n = 0; n < 2; n++) yacc[m][n] = (f32x4){0.f,0.f,0.f,0.f};

    for (int c = 0; c < 8; ++c){
        stage_rows64_512(W1t, c*64, 128, 0,  buf1);            // 64 ff rows, K 0..63
        stage_rows64_512(W1t, c*64, 128, 64, buf1 + 64*64);    // K 64..127
        __syncthreads();
        f32x4 tacc[2];
        #pragma unroll
        for (int m = 0; m < 2; m++) tacc[m] = (f32x4){0.f,0.f,0.f,0.f};
        #pragma unroll
        for (int step = 0; step < 2; ++step){
            const __hip_bfloat16* hs = step ? h1s1 : h1s0;
            #pragma unroll
            for (int kk = 0; kk < 2; ++kk){
                bf16x8 af[2], bw;
                #pragma unroll
                for (int m = 0; m < 2; m++) af[m] = frag(hs, wr*32 + m*16 + lr, kk, ls);
                bw = frag(buf1 + step*64*64, wq*16 + lr, kk, ls);
                #pragma unroll
                for (int m = 0; m < 2; m++)
                    tacc[m] = __builtin_amdgcn_mfma_f32_16x16x32_bf16(af[m], bw, tacc[m], 0, 0, 0);
            }
        }
        // relu + b1 -> buf0 (t1 chunk, [64][64] swizzled)
        #pragma unroll
        for (int m = 0; m < 2; m++){
            #pragma unroll
            for (int j = 0; j < 4; j++){
                int rowl = wr*32 + m*16 + ls*4 + j;
                int cc = wq*16 + lr;
                float v = fmaxf(tacc[m][j] + b1[c*64 + cc], 0.f);
                int slot = (cc >> 3) ^ (rowl & 7), elem = cc & 7;
                ((unsigned short*)buf0)[rowl*64 + slot*8 + elem] = f2bf(v);
            }
        }
        __syncthreads();   // t1 visible; buf1 W1 reads drained
        stage_tile512(W2t, 0, 128, 512, c*64, buf1);           // 128 out cols, K slice
        __syncthreads();
        #pragma unroll
        for (int kk = 0; kk < 2; ++kk){
            bf16x8 af[2], bfg[2];
            #pragma unroll
            for (int m = 0; m < 2; m++) af[m]  = frag(buf0, wr*32 + m*16 + lr, kk, ls);
            #pragma unroll
            for (int n = 0; n < 2; n++) bfg[n] = frag(buf1, wq*32 + n*16 + lr, kk, ls);
            #pragma unroll
            for (int m = 0; m < 2; m++)
                #pragma unroll
                for (int n = 0; n < 2; n++)
                    yacc[m][n] = __builtin_amdgcn_mfma_f32_16x16x32_bf16(af[m], bfg[n], yacc[m][n], 0, 0, 0);
        }
        __syncthreads();   // buf0/buf1 free for next chunk
    }

    // ---- phase D: LN2(y + b2 + h1) -> out (f32) ----
    #pragma unroll
    for (int m = 0; m < 2; m++){
        #pragma unroll
        for (int j = 0; j < 4; j++){
            int rowl = wr*32 + m*16 + ls*4 + j;
            float s = 0.f, q = 0.f;
            #pragma unroll
            for (int n = 0; n < 2; n++){
                int col = wq*32 + n*16 + lr;
                int c6 = col & 63;
                int slot = (c6 >> 3) ^ (rowl & 7), elem = c6 & 7;
                const unsigned short* hp = (const unsigned short*)((col >> 6) ? h1s1 : h1s0);
                float h1v = bf2f(hp[rowl*64 + slot*8 + elem]);
                float v = yacc[m][n][j] + b2[col] + h1v;
                yacc[m][n][j] = v;
                s += v; q += v*v;
            }
            #pragma unroll
            for (int o = 1; o < 16; o <<= 1){
                s += __shfl_xor(s, o);
                q += __shfl_xor(q, o);
            }
            if (lr == 0){
                red0[rowl*4 + wq] = s;
                red1[rowl*4 + wq] = q;
            }
        }
    }
    __syncthreads();
    #pragma unroll
    for (int m = 0; m < 2; m++){
        #pragma unroll
        for (int j = 0; j < 4; j++){
            int rowl = wr*32 + m*16 + ls*4 + j;
            int row = r0 + rowl;
            if (row >= M) continue;
            float s4 = red0[rowl*4+0] + red0[rowl*4+1] + red0[rowl*4+2] + red0[rowl*4+3];
            float q4 = red1[rowl*4+0] + red1[rowl*4+1] + red1[rowl*4+2] + red1[rowl*4+3];
            float mu  = s4 * (1.f/128.f);
            float var = fmaxf(q4 * (1.f/128.f) - mu*mu, 0.f);
            float inv = rsqrtf(var + 1e-5f);
            #pragma unroll
            for (int n = 0; n < 2; n++){
                int col = wq*32 + n*16 + lr;
                out[(size_t)row*128 + col] = (yacc[m][n][j] - mu)*inv*ln2g[col] + ln2b[col];
            }
        }
    }
}

// ---------------- attention: 2 edges/wave, 32 lanes/edge, fp8 kv, 4 chains ------
#define PAIR(jj, dd, b0, b1, b2, b3) { \
    int s0_ = __builtin_amdgcn_readlane(myidx, (jj)); \
    int s1_ = __builtin_amdgcn_readlane(myidx, (jj)+1); \
    int sv_ = half ? s1_ : s0_; \
    unsigned idx_ = (unsigned)sv_*32u + (unsigned)l32; \
    uint2 u_ = kv[idx_]; \
    f32x2 k01 = __builtin_amdgcn_cvt_pk_f32_fp8((int)u_.x, false); \
    f32x2 k23 = __builtin_amdgcn_cvt_pk_f32_fp8((int)u_.x, true); \
    f32x2 v01 = __builtin_amdgcn_cvt_pk_f32_fp8((int)u_.y, false); \
    f32x2 v23 = __builtin_amdgcn_cvt_pk_f32_fp8((int)u_.y, true); \
    float p_ = q0*k01[0] + q1*k01[1] + q2*k23[0] + q3*k23[1]; \
    DPP_ADD(p_, 0xB1); DPP_ADD(p_, 0x4E); \
    float w_ = __builtin_amdgcn_exp2f(p_); \
    dd += w_; \
    b0 = fmaf(w_, v01[0], b0); b1 = fmaf(w_, v01[1], b1); \
    b2 = fmaf(w_, v23[0], b2); b3 = fmaf(w_, v23[1], b3); }

#define PAIRV(jj, dd, b0, b1, b2, b3) { \
    int s0_ = __builtin_amdgcn_readlane(myidx, (jj)); \
    int s1_ = __builtin_amdgcn_readlane(myidx, min((jj)+1, 63)); \
    int sv_ = half ? s1_ : s0_; \
    unsigned idx_ = (unsigned)sv_*32u + (unsigned)l32; \
    uint2 u_ = kv[idx_]; \
    f32x2 k01 = __builtin_amdgcn_cvt_pk_f32_fp8((int)u_.x, false); \
    f32x2 k23 = __builtin_amdgcn_cvt_pk_f32_fp8((int)u_.x, true); \
    f32x2 v01 = __builtin_amdgcn_cvt_pk_f32_fp8((int)u_.y, false); \
    f32x2 v23 = __builtin_amdgcn_cvt_pk_f32_fp8((int)u_.y, true); \
    float p_ = q0*k01[0] + q1*k01[1] + q2*k23[0] + q3*k23[1]; \
    DPP_ADD(p_, 0xB1); DPP_ADD(p_, 0x4E); \
    float w_ = __builtin_amdgcn_exp2f(p_); \
    if ((jj) + half >= cnt) w_ = 0.f; \
    dd += w_; \
    b0 = fmaf(w_, v01[0], b0); b1 = fmaf(w_, v01[1], b1); \
    b2 = fmaf(w_, v23[0], b2); b3 = fmaf(w_, v23[1], b3); }

__global__ __launch_bounds__(256) void k_attn(const __hip_bfloat16* __restrict__ qb,
                                              const uint2* __restrict__ kv,
                                              const int* __restrict__ off,
                                              const int* __restrict__ csr_src,
                                              __hip_bfloat16* __restrict__ a, int N){
    int wid = (blockIdx.x*blockDim.x + threadIdx.x) >> 6;
    int lane = threadIdx.x & 63;
    if (wid >= N) return;
    int half = lane >> 5, l32 = lane & 31;
    ushort4 qu = ((const ushort4*)(qb + (size_t)wid*128))[l32];
    const float SC = 0.25f * 1.44269504f;   // log2e / sqrt(16)
    float q0 = bf2f(qu.x)*SC, q1 = bf2f(qu.y)*SC, q2 = bf2f(qu.z)*SC, q3 = bf2f(qu.w)*SC;
    int beg = off[wid], end = off[wid+1];
    float dA=0, a0A=0, a1A=0, a2A=0, a3A=0;
    float dB=0, a0B=0, a1B=0, a2B=0, a3B=0;
    float dC=0, a0C=0, a1C=0, a2C=0, a3C=0;
    float dDd=0, a0D=0, a1D=0, a2D=0, a3D=0;
    for (int e0 = beg; e0 < end; e0 += 64){
        int myidx = (e0 + lane < end) ? csr_src[e0 + lane] : 0;
        int cnt = min(64, end - e0);
        int j = 0;
        for (; j + 7 < cnt; j += 8){
            PAIR(j,   dA,  a0A, a1A, a2A, a3A);
            PAIR(j+2, dB,  a0B, a1B, a2B, a3B);
            PAIR(j+4, dC,  a0C, a1C, a2C, a3C);
            PAIR(j+6, dDd, a0D, a1D, a2D, a3D);
        }
        for (; j + 3 < cnt; j += 4){
            PAIR(j,   dA, a0A, a1A, a2A, a3A);
            PAIR(j+2, dB, a0B, a1B, a2B, a3B);
        }
        for (; j < cnt; j += 2){
            PAIRV(j, dA, a0A, a1A, a2A, a3A);
        }
    }
    float d  = (dA + dB) + (dC + dDd);
    float a0 = (a0A + a0B) + (a0C + a0D);
    float a1 = (a1A + a1B) + (a1C + a1D);
    float a2 = (a2A + a2B) + (a2C + a2D);
    float a3 = (a3A + a3B) + (a3C + a3D);
    d  += __shfl_xor(d, 32);
    a0 += __shfl_xor(a0, 32);
    a1 += __shfl_xor(a1, 32);
    a2 += __shfl_xor(a2, 32);
    a3 += __shfl_xor(a3, 32);
    if (half == 0){
        float r = (d > 0.f) ? 1.f/d : 0.f;
        ushort4 o;
        o.x = f2bf(a0*r); o.y = f2bf(a1*r); o.z = f2bf(a2*r); o.w = f2bf(a3*r);
        ((ushort4*)(a + (size_t)wid*128))[l32] = o;
    }
}

extern "C" void kernel_launch(void* const* d_in, const int* in_sizes, int n_in,
                              void* d_out, int out_size, void* d_ws, size_t ws_size,
                              hipStream_t stream){
    const float* h    = (const float*)d_in[0];
    const int*   src  = (const int*)  d_in[1];
    const int*   dst  = (const int*)  d_in[2];
    const float* Wq   = (const float*)d_in[3];
    const float* Wk   = (const float*)d_in[4];
    const float* Wv   = (const float*)d_in[5];
    const float* Wo   = (const float*)d_in[6];
    const float* ln1g = (const float*)d_in[7];
    const float* ln1b = (const float*)d_in[8];
    const float* ln2g = (const float*)d_in[9];
    const float* ln2b = (const float*)d_in[10];
    const float* W1   = (const float*)d_in[11];
    const float* b1   = (const float*)d_in[12];
    const float* W2   = (const float*)d_in[13];
    const float* b2   = (const float*)d_in[14];
    float* out = (float*)d_out;

    const int N = in_sizes[0] / D;
    const int E = in_sizes[1];

    char* ws = (char*)d_ws;
    size_t o = 0;
    const size_t row_bf = align256((size_t)N * D * sizeof(__hip_bfloat16));    // 12.8 MB
    const size_t kv_q   = align256((size_t)N * 256);                           // 12.8 MB

    __hip_bfloat16* qb  = (__hip_bfloat16*)(ws + o); o += row_bf;
    unsigned char* kvq  = (unsigned char*)(ws + o); o += kv_q;
    __hip_bfloat16* ab  = (__hip_bfloat16*)(ws + o); o += row_bf;
    __hip_bfloat16* hb  = (__hip_bfloat16*)(ws + o); o += row_bf;
    __hip_bfloat16* Wqkvt = (__hip_bfloat16*)(ws + o); o += align256(384*128*2);
    __hip_bfloat16* W1t   = (__hip_bfloat16*)(ws + o); o += align256(512*128*2);
    __hip_bfloat16* W2t   = (__hip_bfloat16*)(ws + o); o += align256(128*512*2);
    __hip_bfloat16* Wot   = (__hip_bfloat16*)(ws + o); o += align256(128*128*2);
    int* offp  = (int*)(ws + o); o += align256((size_t)(N+1)*4);
    int* bsum256 = (int*)(ws + o); o += align256(1024*4);
    int* ebase = (int*)(ws + o); o += align256(1024*4);
    int* hist2g= (int*)(ws + o); o += align256((size_t)NPART*NSUB*256*4);  // 256KB
    int* lens  = (int*)(ws + o); o += align256((size_t)BINB*8*4);
    int* rlens = (int*)(ws + o); o += align256((size_t)NPART*NPROD*NSUB*4);
    int* qspill= (int*)(ws + o); o += align256(256);
    int* csr   = (int*)(ws + o); o += align256((size_t)E*4);
    unsigned long long* pairs = (unsigned long long*)(ws + o);
    o += align256((size_t)BINB * 8 * BCAP * 8);                  // 50.3 MB
    unsigned* pairs2 = (unsigned*)(ws + o);
    o += align256((size_t)NPART * NPROD * NSUB * RCAP * 4);      // 10.5 MB
    unsigned long long* spill = (unsigned long long*)(ws + o);
    o += align256((size_t)E * 8);                                // 12.8 MB (never used)

    // --- CSR build: bin -> rebin -> count(+sums) -> scan(node-order) -> scatter(+off) ---
    (void)hipMemsetAsync(qspill, 0, 256, stream);
    k_bin3<<<BINB, 256, 0, stream>>>(src, dst, E, N, pairs, lens, spill, qspill);

    k_cast<<<(N*D/4 + 255)/256, 256, 0, stream>>>(h, hb, N*D/4);
    k_prep_all<<<dim3(64, 6), 256, 0, stream>>>(Wq, Wk, Wv, Wo, W1, W2,
                                                Wqkvt, Wot, W1t, W2t);

    k_rebin<<<NPART*NPROD, 256, 0, stream>>>(pairs, lens, pairs2, rlens, spill, qspill, N);
    k_count5<<<NPART*NSUB, 256, 0, stream>>>(pairs2, rlens, spill, qspill, hist2g, bsum256, N);
    k_scanb<<<1, 1024, 0, stream>>>(bsum256, NPART*NSUB, ebase, offp, N);
    k_scatter5<<<NPART*NSUB, 256, 0, stream>>>(pairs2, rlens, spill, qspill,
                                               hist2g, ebase, offp, csr, N);

    int mb = (N + BM - 1)/BM;            // 391
    int mb_pad = ((mb + 7)/8)*8;         // 392
    int mt = (N + TBM - 1)/TBM;          // 782
    int mt_pad = ((mt + 7)/8)*8;         // 784

    // --- QKV projection (q bf16 + kv fp8 epilogue) ---
    k_gemm_qkv<<<dim3(3, mb_pad), 256, 0, stream>>>(hb, Wqkvt, N, qb, kvq);

    // --- sparse attention ---
    k_attn<<<(N*64 + 255)/256, 256, 0, stream>>>(qb, (const uint2*)kvq, offp, csr, ab, N);

    // --- fused tail: Wo + LN1 + FFN1 + FFN2 + LN2 -> out ---
    k_tail<<<mt_pad, 512, 0, stream>>>(ab, h, Wot, ln1g, ln1b,
                                       W1t, b1, W2t, b2, ln2g, ln2b, out, N);
}

// Round 22
// 203.438 us; speedup vs baseline: 1.0531x; 1.0531x over previous
//
#include <hip/hip_runtime.h>
#include <hip/hip_bf16.h>
#include <math.h>

#define D   128
#define FFD 512
#define NPART 8
#define BINB 1024
#define BCAP 768
#define NPROD 32
#define NSUB 32
#define RCAP 320

typedef __attribute__((ext_vector_type(8))) short bf16x8;
typedef __attribute__((ext_vector_type(4))) float f32x4;
typedef __attribute__((ext_vector_type(2))) float f32x2;

static inline size_t align256(size_t x){ return (x + 255) & ~(size_t)255; }

__device__ __forceinline__ float bf2f(unsigned short u){
    union { unsigned int i; float f; } x; x.i = ((unsigned int)u) << 16; return x.f;
}
__device__ __forceinline__ unsigned short f2bf(float f){
    return __builtin_bit_cast(unsigned short, __float2bfloat16(f));
}
// single fp8 e4m3 encode (OCP on gfx950)
__device__ __forceinline__ unsigned char f2fp8(float f){
    return (unsigned char)(__builtin_amdgcn_cvt_pk_fp8_f32(f, f, 0, false) & 0xff);
}

// DPP butterfly add (quad_perm within 4-lane groups)
#define DPP_ADD(x, ctrl) do { \
    int yi_ = __builtin_amdgcn_update_dpp(0, __builtin_bit_cast(int, x), ctrl, 0xf, 0xf, true); \
    x += __builtin_bit_cast(float, yi_); } while(0)

// ---------------- CSR build v7: two-level bin, 3-kernel count/scan/scatter ------
__global__ __launch_bounds__(256) void k_bin3(const int* __restrict__ src,
                                              const int* __restrict__ dst, int E, int N,
                                              unsigned long long* __restrict__ pairs,
                                              int* __restrict__ lens,
                                              unsigned long long* __restrict__ spill,
                                              int* __restrict__ qspill){
    __shared__ int lcur[8];
    int tid = threadIdx.x;
    if (tid < 8) lcur[tid] = 0;
    __syncthreads();
    int slice = (N + 7) >> 3;
    int T = gridDim.x * 256;
    unsigned long long* myreg = pairs + (size_t)blockIdx.x * 8 * BCAP;
    for (int i = blockIdx.x*256 + tid; i < E; i += T){
        int d = __builtin_nontemporal_load(&dst[i]);
        int s = __builtin_nontemporal_load(&src[i]);
        int b = min(d / slice, 7);
        unsigned long long pr = ((unsigned long long)(unsigned)d << 32) | (unsigned)s;
        int slot = atomicAdd(&lcur[b], 1);
        if (slot < BCAP) myreg[(size_t)b*BCAP + slot] = pr;
        else { int p = atomicAdd(qspill, 1); spill[p] = pr; }   // ~never
    }
    __syncthreads();
    if (tid < 8) lens[blockIdx.x*8 + tid] = min(lcur[tid], BCAP);
}

__global__ __launch_bounds__(256) void k_rebin(const unsigned long long* __restrict__ pairs,
                                               const int* __restrict__ lens,
                                               unsigned* __restrict__ pairs2,
                                               int* __restrict__ rlens,
                                               unsigned long long* __restrict__ spill,
                                               int* __restrict__ qspill, int N){
    __shared__ int lcur[NSUB];
    int part = blockIdx.x & 7, ip = blockIdx.x >> 3;
    int tid = threadIdx.x;
    if (tid < NSUB) lcur[tid] = 0;
    __syncthreads();
    int slice = (N + 7) >> 3;
    unsigned subslice = (unsigned)(slice + NSUB - 1) / NSUB;
    int lo_part = part * slice;
    unsigned* outbase = pairs2 + (size_t)(part*NPROD + ip) * NSUB * RCAP;
    for (int seg = ip*(BINB/NPROD); seg < (ip+1)*(BINB/NPROD); ++seg){
        int len = lens[seg*8 + part];
        const unsigned long long* pp = pairs + ((size_t)seg*8 + part)*BCAP;
        for (int i = tid; i < len; i += 256){
            unsigned long long pr = pp[i];
            int d = (int)(pr >> 32);
            unsigned dl = (unsigned)(d - lo_part);
            unsigned sb = dl / subslice;
            int slot = atomicAdd(&lcur[sb], 1);
            if (slot < RCAP)
                outbase[(size_t)sb*RCAP + slot] = ((dl - sb*subslice) << 24) | (unsigned)pr & 0xFFFFFFu;
            else { int p = atomicAdd(qspill, 1); spill[p] = pr; }  // ~never
        }
    }
    __syncthreads();
    if (tid < NSUB) rlens[(part*NPROD + ip)*NSUB + tid] = min(lcur[tid], RCAP);
}

// k_count5: block (p,s) owns ~196 nodes: LDS histogram over its pairs, then
// store hist row to global + block total (replaces cnt[] pass + k_bsum).
__global__ __launch_bounds__(256) void k_count5(const unsigned* __restrict__ pairs2,
                                                const int* __restrict__ rlens,
                                                const unsigned long long* __restrict__ spill,
                                                const int* __restrict__ qspill,
                                                int* __restrict__ hist2g,
                                                int* __restrict__ bsum256, int N){
    __shared__ int hist[256];
    __shared__ int w4[4];
    int part = blockIdx.x & 7, s = blockIdx.x >> 3;
    int slice = (N + 7) >> 3;
    int subslice = (slice + NSUB - 1) / NSUB;
    int lo_part = part*slice;
    int lo = lo_part + s*subslice;
    int part_end = min(lo_part + slice, N);
    int n_sub = max(0, min(subslice, part_end - lo));
    hist[threadIdx.x] = 0;
    __syncthreads();
    for (int ip = 0; ip < NPROD; ++ip){
        int r = (part*NPROD + ip)*NSUB + s;
        int len = rlens[r];
        const unsigned* pp = pairs2 + (size_t)r*RCAP;
        for (int i = threadIdx.x; i < len; i += 256)
            atomicAdd(&hist[pp[i] >> 24], 1);
    }
    int ns = *qspill;
    for (int i = threadIdx.x; i < ns; i += 256){
        int r = (int)(spill[i] >> 32) - lo;
        if (r >= 0 && r < n_sub) atomicAdd(&hist[r], 1);
    }
    __syncthreads();
    int v = hist[threadIdx.x];
    hist2g[blockIdx.x*256 + threadIdx.x] = v;
    #pragma unroll
    for (int o = 1; o < 64; o <<= 1) v += __shfl_xor(v, o);
    if ((threadIdx.x & 63) == 0) w4[threadIdx.x >> 6] = v;
    __syncthreads();
    if (threadIdx.x == 0) bsum256[blockIdx.x] = w4[0] + w4[1] + w4[2] + w4[3];
}

// k_scanb: scan in NODE order. Node range of physical block (part,s) starts at
// part*slice + s*subslice, so logical order l = part*32 + s; physical index
// (blockIdx of count/scatter) = s*8 + part. Read/write through that permutation.
__global__ __launch_bounds__(1024) void k_scanb(const int* __restrict__ bsum, int NB,
                                                int* __restrict__ ebase,
                                                int* __restrict__ off, int N){
    __shared__ int sh[1024];
    int tid = threadIdx.x;
    int phys = ((tid & 31) << 3) | (tid >> 5);   // valid for tid < 256
    int v = (tid < NB) ? bsum[phys] : 0;
    sh[tid] = v; __syncthreads();
    for (int o = 1; o < 1024; o <<= 1){
        int t = (tid >= o) ? sh[tid-o] : 0;
        __syncthreads();
        sh[tid] += t;
        __syncthreads();
    }
    if (tid < NB) ebase[phys] = sh[tid] - v;
    if (tid == NB-1) off[N] = sh[tid];
}

// k_scatter5: block (p,s): load its hist row, LDS prefix-scan + ebase -> writes
// off[] for its range and scatters csr into the private contiguous slice.
__global__ __launch_bounds__(256) void k_scatter5(const unsigned* __restrict__ pairs2,
                                                  const int* __restrict__ rlens,
                                                  const unsigned long long* __restrict__ spill,
                                                  const int* __restrict__ qspill,
                                                  const int* __restrict__ hist2g,
                                                  const int* __restrict__ ebase,
                                                  int* __restrict__ off,
                                                  int* __restrict__ csr_src, int N){
    __shared__ int sh[256];
    __shared__ int curl[256];
    int part = blockIdx.x & 7, s = blockIdx.x >> 3;
    int tid = threadIdx.x;
    int slice = (N + 7) >> 3;
    int subslice = (slice + NSUB - 1) / NSUB;
    int lo_part = part*slice;
    int lo = lo_part + s*subslice;
    int part_end = min(lo_part + slice, N);
    int n_sub = max(0, min(subslice, part_end - lo));
    int v = hist2g[blockIdx.x*256 + tid];
    sh[tid] = v; __syncthreads();
    for (int o = 1; o < 256; o <<= 1){
        int t = (tid >= o) ? sh[tid-o] : 0;
        __syncthreads();
        sh[tid] += t;
        __syncthreads();
    }
    int base = ebase[blockIdx.x];
    int start = base + sh[tid] - v;
    curl[tid] = start;
    if (tid < n_sub) off[lo + tid] = start;
    __syncthreads();
    for (int ip = 0; ip < NPROD; ++ip){
        int r = (part*NPROD + ip)*NSUB + s;
        int len = rlens[r];
        const unsigned* pp = pairs2 + (size_t)r*RCAP;
        for (int i = tid; i < len; i += 256){
            unsigned e = pp[i];
            int pos = atomicAdd(&curl[e >> 24], 1);
            csr_src[pos] = (int)(e & 0xFFFFFFu);
        }
    }
    int ns = *qspill;
    for (int i = tid; i < ns; i += 256){
        unsigned long long pr = spill[i];
        int r = (int)(pr >> 32) - lo;
        if (r >= 0 && r < n_sub){
            int pos = atomicAdd(&curl[r], 1);
            csr_src[pos] = (int)(unsigned)pr;
        }
    }
}

// ---------------- prep ----------------
__global__ __launch_bounds__(256) void k_cast(const float* __restrict__ x,
                                              __hip_bfloat16* __restrict__ y, int n4){
    int i = blockIdx.x*blockDim.x + threadIdx.x;
    if (i >= n4) return;
    float4 f = ((const float4*)x)[i];
    ushort4 u;
    u.x = f2bf(f.x); u.y = f2bf(f.y);
    u.z = f2bf(f.z); u.w = f2bf(f.w);
    ((ushort4*)y)[i] = u;
}

// merged weight transpose+cast. Wk/Wv rows permuted for the 32-lane attn layout.
__global__ __launch_bounds__(256) void k_prep_all(
    const float* __restrict__ Wq, const float* __restrict__ Wk,
    const float* __restrict__ Wv, const float* __restrict__ Wo,
    const float* __restrict__ W1, const float* __restrict__ W2,
    __hip_bfloat16* __restrict__ Wqkvt, __hip_bfloat16* __restrict__ Wot,
    __hip_bfloat16* __restrict__ W1t,   __hip_bfloat16* __restrict__ W2t){
    const float* W; __hip_bfloat16* Wt; int K, Nc;
    int y = blockIdx.y;
    switch (y){
        case 0: W = Wq; Wt = Wqkvt; K = 128; Nc = 128; break;
        case 1: W = Wk; Wt = Wqkvt; K = 128; Nc = 128; break;
        case 2: W = Wv; Wt = Wqkvt; K = 128; Nc = 128; break;
        case 3: W = Wo; Wt = Wot;   K = 128; Nc = 128; break;
        case 4: W = W1; Wt = W1t;   K = 128; Nc = 512; break;
        default: W = W2; Wt = W2t;  K = 512; Nc = 128; break;
    }
    int total = K*Nc;
    for (int id = blockIdx.x*256 + threadIdx.x; id < total; id += 256*gridDim.x){
        int n = id / K, kk = id % K;
        size_t drow;
        if (y == 1)      drow = 128 + 8*(n>>2) + (n&3);
        else if (y == 2) drow = 128 + 8*(n>>2) + 4 + (n&3);
        else             drow = n;
        Wt[drow*K + kk] = __float2bfloat16(W[(size_t)kk*Nc + n]);
    }
}

// ---------------- MFMA helpers ----------------
#define BM 128
#define BN 128
#define BK 64

__device__ __forceinline__ bool tile_coords(int M, int &r0, int &c0){
    int ncols = gridDim.x;
    int f = blockIdx.y * ncols + blockIdx.x;
    int xcd = f & 7, s = f >> 3;
    int c = s % ncols, rl = s / ncols;
    int r = rl*8 + xcd;
    r0 = r*BM; c0 = c*BN;
    return r0 < M;
}

// stage 128 rows x 64 K (bf16), XOR-swizzled source (256-thread version)
__device__ __forceinline__ void stage_tile(const __hip_bfloat16* __restrict__ src,
                                           int row_base, int row_limit, int ldK, int k0,
                                           __hip_bfloat16* lds){
    int tid = threadIdx.x;
    int wave = tid >> 6;
    #pragma unroll
    for (int i = 0; i < 4; ++i){
        int c = i*256 + tid;
        int r = c >> 3, s = c & 7;
        int sg = s ^ (r & 7);
        int gr = row_base + r; if (gr >= row_limit) gr = row_limit - 1;
        const __hip_bfloat16* gp = src + (size_t)gr*ldK + k0 + sg*8;
        char* lp = (char*)lds + (i*256 + wave*64)*16;
        __builtin_amdgcn_global_load_lds((const __attribute__((address_space(1))) void*)gp,
                                         (__attribute__((address_space(3))) void*)lp,
                                         16, 0, 0);
    }
}

// 512-thread versions
__device__ __forceinline__ void stage_tile512(const __hip_bfloat16* __restrict__ src,
                                              int row_base, int row_limit, int ldK, int k0,
                                              __hip_bfloat16* lds){
    int tid = threadIdx.x;
    int wave = tid >> 6;
    #pragma unroll
    for (int i = 0; i < 2; ++i){
        int c = i*512 + tid;
        int r = c >> 3, s = c & 7;
        int sg = s ^ (r & 7);
        int gr = row_base + r; if (gr >= row_limit) gr = row_limit - 1;
        const __hip_bfloat16* gp = src + (size_t)gr*ldK + k0 + sg*8;
        char* lp = (char*)lds + (i*512 + wave*64)*16;
        __builtin_amdgcn_global_load_lds((const __attribute__((address_space(1))) void*)gp,
                                         (__attribute__((address_space(3))) void*)lp,
                                         16, 0, 0);
    }
}

// 64 rows x 64 K, 512 threads, no clamp (full weight rows)
__device__ __forceinline__ void stage_rows64_512(const __hip_bfloat16* __restrict__ src,
                                                 int row_base, int ldK, int k0,
                                                 __hip_bfloat16* lds){
    int tid = threadIdx.x;
    int wave = tid >> 6;
    int c = tid;                      // 512 chunks = 64 rows x 8 slots
    int r = c >> 3, s = c & 7;
    int sg = s ^ (r & 7);
    const __hip_bfloat16* gp = src + (size_t)(row_base + r)*ldK + k0 + sg*8;
    char* lp = (char*)lds + (wave*64)*16;
    __builtin_amdgcn_global_load_lds((const __attribute__((address_space(1))) void*)gp,
                                     (__attribute__((address_space(3))) void*)lp,
                                     16, 0, 0);
}

// 64 rows x 64 K, 512 threads, row-clamped (activation tiles)
__device__ __forceinline__ void stage_rows64c_512(const __hip_bfloat16* __restrict__ src,
                                                  int row_base, int row_limit, int ldK, int k0,
                                                  __hip_bfloat16* lds){
    int tid = threadIdx.x;
    int wave = tid >> 6;
    int c = tid;
    int r = c >> 3, s = c & 7;
    int sg = s ^ (r & 7);
    int gr = row_base + r; if (gr >= row_limit) gr = row_limit - 1;
    const __hip_bfloat16* gp = src + (size_t)gr*ldK + k0 + sg*8;
    char* lp = (char*)lds + (wave*64)*16;
    __builtin_amdgcn_global_load_lds((const __attribute__((address_space(1))) void*)gp,
                                     (__attribute__((address_space(3))) void*)lp,
                                     16, 0, 0);
}

// read A/B fragment from a swizzled [rows][64] buffer
__device__ __forceinline__ bf16x8 frag(const __hip_bfloat16* buf, int R, int kk, int ls){
    int sl = (kk*4 + ls) ^ (R & 7);
    return *(const bf16x8*)((const char*)buf + R*128 + sl*16);
}

// ---------------- QKV GEMM ----------------
__global__ __launch_bounds__(256) void k_gemm_qkv(
    const __hip_bfloat16* __restrict__ A,   // [M][128]
    const __hip_bfloat16* __restrict__ Bt,  // [384][128]
    int M,
    __hip_bfloat16* __restrict__ qb, unsigned char* __restrict__ kvq){
    __shared__ __hip_bfloat16 As[BM*BK];
    __shared__ __hip_bfloat16 Bs[BN*BK];
    int r0, c0;
    if (!tile_coords(M, r0, c0)) return;
    int tid = threadIdx.x;
    int lane = tid & 63, wave = tid >> 6;
    int wr = wave >> 1, wc = wave & 1;
    int lr = lane & 15, ls = lane >> 4;

    f32x4 acc[4][4];
    #pragma unroll
    for (int m = 0; m < 4; m++)
        #pragma unroll
        for (int n = 0; n < 4; n++) acc[m][n] = (f32x4){0.f,0.f,0.f,0.f};

    for (int k0 = 0; k0 < 128; k0 += BK){
        stage_tile(A,  r0, M,   128, k0, As);
        stage_tile(Bt, c0, 384, 128, k0, Bs);
        __syncthreads();
        #pragma unroll
        for (int kk = 0; kk < 2; ++kk){
            bf16x8 af[4], bfg[4];
            #pragma unroll
            for (int m = 0; m < 4; m++) af[m]  = frag(As, wr*64 + m*16 + lr, kk, ls);
            #pragma unroll
            for (int n = 0; n < 4; n++) bfg[n] = frag(Bs, wc*64 + n*16 + lr, kk, ls);
            #pragma unroll
            for (int m = 0; m < 4; m++)
                #pragma unroll
                for (int n = 0; n < 4; n++)
                    acc[m][n] = __builtin_amdgcn_mfma_f32_16x16x32_bf16(af[m], bfg[n], acc[m][n], 0, 0, 0);
        }
        __syncthreads();
    }

    int region = c0 >> 7;    // 0=q, 1=kv bytes 0..127, 2=kv bytes 128..255
    #pragma unroll
    for (int n = 0; n < 4; n++){
        int c16 = wc*64 + n*16 + lr;
        #pragma unroll
        for (int m = 0; m < 4; m++){
            #pragma unroll
            for (int j = 0; j < 4; j++){
                int row = r0 + wr*64 + m*16 + ls*4 + j;
                if (row >= M) continue;
                float v = acc[m][n][j];
                if (region == 0)
                    ((unsigned short*)qb)[(size_t)row*128 + c16] = f2bf(v);
                else
                    kvq[(size_t)row*256 + (region-1)*128 + c16] = f2fp8(v);
            }
        }
    }
}

// ---------------- fused tail v4: 64-row blocks, 512 threads, 40KB LDS ----------
#define TBM 64
__global__ __launch_bounds__(512) void k_tail(
    const __hip_bfloat16* __restrict__ ab, const float* __restrict__ h,
    const __hip_bfloat16* __restrict__ Wot,
    const float* __restrict__ ln1g, const float* __restrict__ ln1b,
    const __hip_bfloat16* __restrict__ W1t, const float* __restrict__ b1,
    const __hip_bfloat16* __restrict__ W2t, const float* __restrict__ b2,
    const float* __restrict__ ln2g, const float* __restrict__ ln2b,
    float* __restrict__ out, int M){
    __shared__ char smem[40960];
    __hip_bfloat16* buf0 = (__hip_bfloat16*)smem;            // 8KB
    __hip_bfloat16* buf1 = (__hip_bfloat16*)(smem + 8192);   // 16KB
    __hip_bfloat16* h1s0 = (__hip_bfloat16*)(smem + 24576);  // 8KB
    __hip_bfloat16* h1s1 = (__hip_bfloat16*)(smem + 32768);  // 8KB
    float* red0 = (float*)smem;              // overlay on buf0 (LN phases only)
    float* red1 = (float*)(smem + 1024);
    int f = blockIdx.x;
    int r0 = ((f >> 3)*8 + (f & 7)) * TBM;   // XCD swizzle (bijective, grid%8==0)
    if (r0 >= M) return;
    int tid = threadIdx.x;
    int lane = tid & 63, wave = tid >> 6;
    int wr = wave >> 2, wq = wave & 3;
    int lr = lane & 15, ls = lane >> 4;

    f32x4 acc[2][2];
    #pragma unroll
    for (int m = 0; m < 2; m++)
        #pragma unroll
        for (int n = 0; n < 2; n++) acc[m][n] = (f32x4){0.f,0.f,0.f,0.f};

    // ---- phase A: o = ab @ Wot ----
    for (int k0 = 0; k0 < 128; k0 += BK){
        stage_rows64c_512(ab, r0, M, 128, k0, buf0);
        stage_tile512(Wot, 0, 128, 128, k0, buf1);
        __syncthreads();
        #pragma unroll
        for (int kk = 0; kk < 2; ++kk){
            bf16x8 af[2], bfg[2];
            #pragma unroll
            for (int m = 0; m < 2; m++) af[m]  = frag(buf0, wr*32 + m*16 + lr, kk, ls);
            #pragma unroll
            for (int n = 0; n < 2; n++) bfg[n] = frag(buf1, wq*32 + n*16 + lr, kk, ls);
            #pragma unroll
            for (int m = 0; m < 2; m++)
                #pragma unroll
                for (int n = 0; n < 2; n++)
                    acc[m][n] = __builtin_amdgcn_mfma_f32_16x16x32_bf16(af[m], bfg[n], acc[m][n], 0, 0, 0);
        }
        __syncthreads();
    }

    // ---- phase B: LN1(o + h) -> h1s (buf0 dead; red overlays it) ----
    #pragma unroll
    for (int m = 0; m < 2; m++){
        #pragma unroll
        for (int j = 0; j < 4; j++){
            int rowl = wr*32 + m*16 + ls*4 + j;
            int row = r0 + rowl;
            float s = 0.f, q = 0.f;
            #pragma unroll
            for (int n = 0; n < 2; n++){
                int col = wq*32 + n*16 + lr;
                float rv = (row < M) ? h[(size_t)row*128 + col] : 0.f;
                float v = acc[m][n][j] + rv;
                acc[m][n][j] = v;
                s += v; q += v*v;
            }
            #pragma unroll
            for (int o = 1; o < 16; o <<= 1){
                s += __shfl_xor(s, o);
                q += __shfl_xor(q, o);
            }
            if (lr == 0){
                red0[rowl*4 + wq] = s;
                red1[rowl*4 + wq] = q;
            }
        }
    }
    __syncthreads();
    #pragma unroll
    for (int m = 0; m < 2; m++){
        #pragma unroll
        for (int j = 0; j < 4; j++){
            int rowl = wr*32 + m*16 + ls*4 + j;
            float s4 = red0[rowl*4+0] + red0[rowl*4+1] + red0[rowl*4+2] + red0[rowl*4+3];
            float q4 = red1[rowl*4+0] + red1[rowl*4+1] + red1[rowl*4+2] + red1[rowl*4+3];
            float mu  = s4 * (1.f/128.f);
            float var = fmaxf(q4 * (1.f/128.f) - mu*mu, 0.f);
            float inv = rsqrtf(var + 1e-5f);
            #pragma unroll
            for (int n = 0; n < 2; n++){
                int col = wq*32 + n*16 + lr;
                float o = (acc[m][n][j] - mu)*inv*ln1g[col] + ln1b[col];
                int c6 = col & 63;
                int slot = (c6 >> 3) ^ (rowl & 7), elem = c6 & 7;
                unsigned short* dstp = (unsigned short*)((col >> 6) ? h1s1 : h1s0);
                dstp[rowl*64 + slot*8 + elem] = f2bf(o);
            }
        }
    }
    __syncthreads();

    // ---- phase C: 8 FFN chunks of 64 ff-cols ----
    f32x4 yacc[2][2];
    #pragma unroll
    for (int m = 0; m < 2; m++)
        #pragma unroll
        for (int n = 0; n < 2; n++) yacc[m][n] = (f32x4){0.f,0.f,0.f,0.f};

    for (int c = 0; c < 8; ++c){
        stage_rows64_512(W1t, c*64, 128, 0,  buf1);            // 64 ff rows, K 0..63
        stage_rows64_512(W1t, c*64, 128, 64, buf1 + 64*64);    // K 64..127
        __syncthreads();
        f32x4 tacc[2];
        #pragma unroll
        for (int m = 0; m < 2; m++) tacc[m] = (f32x4){0.f,0.f,0.f,0.f};
        #pragma unroll
        for (int step = 0; step < 2; ++step){
            const __hip_bfloat16* hs = step ? h1s1 : h1s0;
            #pragma unroll
            for (int kk = 0; kk < 2; ++kk){
                bf16x8 af[2], bw;
                #pragma unroll
                for (int m = 0; m < 2; m++) af[m] = frag(hs, wr*32 + m*16 + lr, kk, ls);
                bw = frag(buf1 + step*64*64, wq*16 + lr, kk, ls);
                #pragma unroll
                for (int m = 0; m < 2; m++)
                    tacc[m] = __builtin_amdgcn_mfma_f32_16x16x32_bf16(af[m], bw, tacc[m], 0, 0, 0);
            }
        }
        // relu + b1 -> buf0 (t1 chunk, [64][64] swizzled)
        #pragma unroll
        for (int m = 0; m < 2; m++){
            #pragma unroll
            for (int j = 0; j < 4; j++){
                int rowl = wr*32 + m*16 + ls*4 + j;
                int cc = wq*16 + lr;
                float v = fmaxf(tacc[m][j] + b1[c*64 + cc], 0.f);
                int slot = (cc >> 3) ^ (rowl & 7), elem = cc & 7;
                ((unsigned short*)buf0)[rowl*64 + slot*8 + elem] = f2bf(v);
            }
        }
        __syncthreads();   // t1 visible; buf1 W1 reads drained
        stage_tile512(W2t, 0, 128, 512, c*64, buf1);           // 128 out cols, K slice
        __syncthreads();
        #pragma unroll
        for (int kk = 0; kk < 2; ++kk){
            bf16x8 af[2], bfg[2];
            #pragma unroll
            for (int m = 0; m < 2; m++) af[m]  = frag(buf0, wr*32 + m*16 + lr, kk, ls);
            #pragma unroll
            for (int n = 0; n < 2; n++) bfg[n] = frag(buf1, wq*32 + n*16 + lr, kk, ls);
            #pragma unroll
            for (int m = 0; m < 2; m++)
                #pragma unroll
                for (int n = 0; n < 2; n++)
                    yacc[m][n] = __builtin_amdgcn_mfma_f32_16x16x32_bf16(af[m], bfg[n], yacc[m][n], 0, 0, 0);
        }
        __syncthreads();   // buf0/buf1 free for next chunk
    }

    // ---- phase D: LN2(y + b2 + h1) -> out (f32) ----
    #pragma unroll
    for (int m = 0; m < 2; m++){
        #pragma unroll
        for (int j = 0; j < 4; j++){
            int rowl = wr*32 + m*16 + ls*4 + j;
            float s = 0.f, q = 0.f;
            #pragma unroll
            for (int n = 0; n < 2; n++){
                int col = wq*32 + n*16 + lr;
                int c6 = col & 63;
                int slot = (c6 >> 3) ^ (rowl & 7), elem = c6 & 7;
                const unsigned short* hp = (const unsigned short*)((col >> 6) ? h1s1 : h1s0);
                float h1v = bf2f(hp[rowl*64 + slot*8 + elem]);
                float v = yacc[m][n][j] + b2[col] + h1v;
                yacc[m][n][j] = v;
                s += v; q += v*v;
            }
            #pragma unroll
            for (int o = 1; o < 16; o <<= 1){
                s += __shfl_xor(s, o);
                q += __shfl_xor(q, o);
            }
            if (lr == 0){
                red0[rowl*4 + wq] = s;
                red1[rowl*4 + wq] = q;
            }
        }
    }
    __syncthreads();
    #pragma unroll
    for (int m = 0; m < 2; m++){
        #pragma unroll
        for (int j = 0; j < 4; j++){
            int rowl = wr*32 + m*16 + ls*4 + j;
            int row = r0 + rowl;
            if (row >= M) continue;
            float s4 = red0[rowl*4+0] + red0[rowl*4+1] + red0[rowl*4+2] + red0[rowl*4+3];
            float q4 = red1[rowl*4+0] + red1[rowl*4+1] + red1[rowl*4+2] + red1[rowl*4+3];
            float mu  = s4 * (1.f/128.f);
            float var = fmaxf(q4 * (1.f/128.f) - mu*mu, 0.f);
            float inv = rsqrtf(var + 1e-5f);
            #pragma unroll
            for (int n = 0; n < 2; n++){
                int col = wq*32 + n*16 + lr;
                out[(size_t)row*128 + col] = (yacc[m][n][j] - mu)*inv*ln2g[col] + ln2b[col];
            }
        }
    }
}

// ---------------- attention: 2 edges/wave, 32 lanes/edge, fp8 kv (round-19) -----
#define PAIR(jj, dd, b0, b1, b2, b3) { \
    int s0_ = __builtin_amdgcn_readlane(myidx, (jj)); \
    int s1_ = __builtin_amdgcn_readlane(myidx, (jj)+1); \
    int sv_ = half ? s1_ : s0_; \
    uint2 u_ = kv[(size_t)(unsigned)sv_*32 + l32]; \
    f32x2 k01 = __builtin_amdgcn_cvt_pk_f32_fp8((int)u_.x, false); \
    f32x2 k23 = __builtin_amdgcn_cvt_pk_f32_fp8((int)u_.x, true); \
    f32x2 v01 = __builtin_amdgcn_cvt_pk_f32_fp8((int)u_.y, false); \
    f32x2 v23 = __builtin_amdgcn_cvt_pk_f32_fp8((int)u_.y, true); \
    float p_ = q0*k01[0] + q1*k01[1] + q2*k23[0] + q3*k23[1]; \
    DPP_ADD(p_, 0xB1); DPP_ADD(p_, 0x4E); \
    float w_ = __builtin_amdgcn_exp2f(p_); \
    dd += w_; \
    b0 = fmaf(w_, v01[0], b0); b1 = fmaf(w_, v01[1], b1); \
    b2 = fmaf(w_, v23[0], b2); b3 = fmaf(w_, v23[1], b3); }

#define PAIRV(jj, dd, b0, b1, b2, b3) { \
    int s0_ = __builtin_amdgcn_readlane(myidx, (jj)); \
    int s1_ = __builtin_amdgcn_readlane(myidx, min((jj)+1, 63)); \
    int sv_ = half ? s1_ : s0_; \
    uint2 u_ = kv[(size_t)(unsigned)sv_*32 + l32]; \
    f32x2 k01 = __builtin_amdgcn_cvt_pk_f32_fp8((int)u_.x, false); \
    f32x2 k23 = __builtin_amdgcn_cvt_pk_f32_fp8((int)u_.x, true); \
    f32x2 v01 = __builtin_amdgcn_cvt_pk_f32_fp8((int)u_.y, false); \
    f32x2 v23 = __builtin_amdgcn_cvt_pk_f32_fp8((int)u_.y, true); \
    float p_ = q0*k01[0] + q1*k01[1] + q2*k23[0] + q3*k23[1]; \
    DPP_ADD(p_, 0xB1); DPP_ADD(p_, 0x4E); \
    float w_ = __builtin_amdgcn_exp2f(p_); \
    if ((jj) + half >= cnt) w_ = 0.f; \
    dd += w_; \
    b0 = fmaf(w_, v01[0], b0); b1 = fmaf(w_, v01[1], b1); \
    b2 = fmaf(w_, v23[0], b2); b3 = fmaf(w_, v23[1], b3); }

__global__ __launch_bounds__(256) void k_attn(const __hip_bfloat16* __restrict__ qb,
                                              const uint2* __restrict__ kv,
                                              const int* __restrict__ off,
                                              const int* __restrict__ csr_src,
                                              __hip_bfloat16* __restrict__ a, int N){
    int wid = (blockIdx.x*blockDim.x + threadIdx.x) >> 6;
    int lane = threadIdx.x & 63;
    if (wid >= N) return;
    int half = lane >> 5, l32 = lane & 31;
    ushort4 qu = ((const ushort4*)(qb + (size_t)wid*128))[l32];
    const float SC = 0.25f * 1.44269504f;   // log2e / sqrt(16)
    float q0 = bf2f(qu.x)*SC, q1 = bf2f(qu.y)*SC, q2 = bf2f(qu.z)*SC, q3 = bf2f(qu.w)*SC;
    int beg = off[wid], end = off[wid+1];
    float dA=0, a0A=0, a1A=0, a2A=0, a3A=0;
    float dB=0, a0B=0, a1B=0, a2B=0, a3B=0;
    for (int e0 = beg; e0 < end; e0 += 64){
        int myidx = (e0 + lane < end) ? csr_src[e0 + lane] : 0;
        int cnt = min(64, end - e0);
        int j = 0;
        for (; j + 3 < cnt; j += 4){
            PAIR(j,   dA, a0A, a1A, a2A, a3A);
            PAIR(j+2, dB, a0B, a1B, a2B, a3B);
        }
        for (; j < cnt; j += 2){
            PAIRV(j, dA, a0A, a1A, a2A, a3A);
        }
    }
    float d  = dA + dB;
    float a0 = a0A + a0B, a1 = a1A + a1B, a2 = a2A + a2B, a3 = a3A + a3B;
    d  += __shfl_xor(d, 32);
    a0 += __shfl_xor(a0, 32);
    a1 += __shfl_xor(a1, 32);
    a2 += __shfl_xor(a2, 32);
    a3 += __shfl_xor(a3, 32);
    if (half == 0){
        float r = (d > 0.f) ? 1.f/d : 0.f;
        ushort4 o;
        o.x = f2bf(a0*r); o.y = f2bf(a1*r); o.z = f2bf(a2*r); o.w = f2bf(a3*r);
        ((ushort4*)(a + (size_t)wid*128))[l32] = o;
    }
}

extern "C" void kernel_launch(void* const* d_in, const int* in_sizes, int n_in,
                              void* d_out, int out_size, void* d_ws, size_t ws_size,
                              hipStream_t stream){
    const float* h    = (const float*)d_in[0];
    const int*   src  = (const int*)  d_in[1];
    const int*   dst  = (const int*)  d_in[2];
    const float* Wq   = (const float*)d_in[3];
    const float* Wk   = (const float*)d_in[4];
    const float* Wv   = (const float*)d_in[5];
    const float* Wo   = (const float*)d_in[6];
    const float* ln1g = (const float*)d_in[7];
    const float* ln1b = (const float*)d_in[8];
    const float* ln2g = (const float*)d_in[9];
    const float* ln2b = (const float*)d_in[10];
    const float* W1   = (const float*)d_in[11];
    const float* b1   = (const float*)d_in[12];
    const float* W2   = (const float*)d_in[13];
    const float* b2   = (const float*)d_in[14];
    float* out = (float*)d_out;

    const int N = in_sizes[0] / D;
    const int E = in_sizes[1];

    char* ws = (char*)d_ws;
    size_t o = 0;
    const size_t row_bf = align256((size_t)N * D * sizeof(__hip_bfloat16));    // 12.8 MB
    const size_t kv_q   = align256((size_t)N * 256);                           // 12.8 MB

    __hip_bfloat16* qb  = (__hip_bfloat16*)(ws + o); o += row_bf;
    unsigned char* kvq  = (unsigned char*)(ws + o); o += kv_q;
    __hip_bfloat16* ab  = (__hip_bfloat16*)(ws + o); o += row_bf;
    __hip_bfloat16* hb  = (__hip_bfloat16*)(ws + o); o += row_bf;
    __hip_bfloat16* Wqkvt = (__hip_bfloat16*)(ws + o); o += align256(384*128*2);
    __hip_bfloat16* W1t   = (__hip_bfloat16*)(ws + o); o += align256(512*128*2);
    __hip_bfloat16* W2t   = (__hip_bfloat16*)(ws + o); o += align256(128*512*2);
    __hip_bfloat16* Wot   = (__hip_bfloat16*)(ws + o); o += align256(128*128*2);
    int* offp  = (int*)(ws + o); o += align256((size_t)(N+1)*4);
    int* bsum256 = (int*)(ws + o); o += align256(1024*4);
    int* ebase = (int*)(ws + o); o += align256(1024*4);
    int* hist2g= (int*)(ws + o); o += align256((size_t)NPART*NSUB*256*4);  // 256KB
    int* lens  = (int*)(ws + o); o += align256((size_t)BINB*8*4);
    int* rlens = (int*)(ws + o); o += align256((size_t)NPART*NPROD*NSUB*4);
    int* qspill= (int*)(ws + o); o += align256(256);
    int* csr   = (int*)(ws + o); o += align256((size_t)E*4);
    unsigned long long* pairs = (unsigned long long*)(ws + o);
    o += align256((size_t)BINB * 8 * BCAP * 8);                  // 50.3 MB
    unsigned* pairs2 = (unsigned*)(ws + o);
    o += align256((size_t)NPART * NPROD * NSUB * RCAP * 4);      // 10.5 MB
    unsigned long long* spill = (unsigned long long*)(ws + o);
    o += align256((size_t)E * 8);                                // 12.8 MB (never used)

    // --- CSR build: bin -> rebin -> count(+sums) -> scan(node-order) -> scatter(+off) ---
    (void)hipMemsetAsync(qspill, 0, 256, stream);
    k_bin3<<<BINB, 256, 0, stream>>>(src, dst, E, N, pairs, lens, spill, qspill);

    k_cast<<<(N*D/4 + 255)/256, 256, 0, stream>>>(h, hb, N*D/4);
    k_prep_all<<<dim3(64, 6), 256, 0, stream>>>(Wq, Wk, Wv, Wo, W1, W2,
                                                Wqkvt, Wot, W1t, W2t);

    k_rebin<<<NPART*NPROD, 256, 0, stream>>>(pairs, lens, pairs2, rlens, spill, qspill, N);
    k_count5<<<NPART*NSUB, 256, 0, stream>>>(pairs2, rlens, spill, qspill, hist2g, bsum256, N);
    k_scanb<<<1, 1024, 0, stream>>>(bsum256, NPART*NSUB, ebase, offp, N);
    k_scatter5<<<NPART*NSUB, 256, 0, stream>>>(pairs2, rlens, spill, qspill,
                                               hist2g, ebase, offp, csr, N);

    int mb = (N + BM - 1)/BM;            // 391
    int mb_pad = ((mb + 7)/8)*8;         // 392
    int mt = (N + TBM - 1)/TBM;          // 782
    int mt_pad = ((mt + 7)/8)*8;         // 784

    // --- QKV projection (q bf16 + kv fp8 epilogue) ---
    k_gemm_qkv<<<dim3(3, mb_pad), 256, 0, stream>>>(hb, Wqkvt, N, qb, kvq);

    // --- sparse attention ---
    k_attn<<<(N*64 + 255)/256, 256, 0, stream>>>(qb, (const uint2*)kvq, offp, csr, ab, N);

    // --- fused tail: Wo + LN1 + FFN1 + FFN2 + LN2 -> out ---
    k_tail<<<mt_pad, 512, 0, stream>>>(ab, h, Wot, ln1g, ln1b,
                                       W1t, b1, W2t, b2, ln2g, ln2b, out, N);
}